// Round 6
// baseline (893.360 us; speedup 1.0000x reference)
//
#include <hip/hip_runtime.h>
#include <math.h>

// ---------------------------------------------------------------------------
// DAHead: B=8, Cin=512, Ci=128, H=W=64, N=4096, Ck=16, NC=19.
// R6: all conv inputs pre-transposed channel-blocked bf16 [b][C/16][4096][16]
//     -> conv staging is contiguous uint4 loads (no scalar gather, no f2bf).
//     conv1c emits bh/blo only (bufB dropped); cam_feat reconstructs fp32.
// ws (byte offsets):
//   bufA@0 (16MB fp32: conv1p out -> conv2c out)
//   bh@16M, blo@24M (8MB bf16 each, conv1c out, channel-major [b][c][n])
//   xh@32M, xl@64M (32MB each, blocked; dead after conv1c) then:
//     egy_part@32M(4M) qt@36M kt@37M rowmax@38M egy@38.25M vb@40M(8M)
//     bufD@48M(16M) pam_bfB@64M(8M) camh@72M(8M) caml@80M(8M)
//   weights@96M.. (~4.3MB)
// ---------------------------------------------------------------------------

typedef __attribute__((ext_vector_type(8)))  short short8;
typedef __attribute__((ext_vector_type(16))) float f32x16;

__device__ inline unsigned short f2bf(float f) {
    union { float f; unsigned u; } v; v.f = f;
    unsigned r = v.u + 0x7fffu + ((v.u >> 16) & 1u);   // RNE
    return (unsigned short)(r >> 16);
}
__device__ inline float bf2f(unsigned short h) {
    union { unsigned u; float f; } v; v.u = ((unsigned)h) << 16;
    return v.f;
}

// ---- weight prepack: W[co][cin][9] fp32 -> wpack[chunk][tap][co128][16] ---
__global__ __launch_bounds__(256) void wpack_kernel(
    const float* __restrict__ W, unsigned short* __restrict__ wp, int Cin, int total)
{
    int idx = blockIdx.x * 256 + threadIdx.x;
    if (idx >= total) return;
    int chunk = idx / 18432;
    int rem   = idx - chunk * 18432;
    int tap   = rem >> 11;
    int rem2  = rem & 2047;
    int co    = rem2 >> 4;
    int ci    = rem2 & 15;
    int cin   = (chunk << 4) + ci;
    wp[idx] = f2bf(W[((size_t)co * Cin + cin) * 9 + tap]);
}

__global__ __launch_bounds__(256) void wpack_split_kernel(
    const float* __restrict__ W, unsigned short* __restrict__ wph,
    unsigned short* __restrict__ wpl, int Cin, int total)
{
    int idx = blockIdx.x * 256 + threadIdx.x;
    if (idx >= total) return;
    int chunk = idx / 18432;
    int rem   = idx - chunk * 18432;
    int tap   = rem >> 11;
    int rem2  = rem & 2047;
    int co    = rem2 >> 4;
    int ci    = rem2 & 15;
    int cin   = (chunk << 4) + ci;
    float w = W[((size_t)co * Cin + cin) * 9 + tap];
    unsigned short hi = f2bf(w);
    wph[idx] = hi;
    wpl[idx] = f2bf(w - bf2f(hi));
}

// ---- x split+transpose: x fp32 [b][512][4096] -> xh/xl blocked bf16 -------
// [b][32][4096][16].  grid (32 ch, 8 b), 256 thr; in-register transpose.
__global__ __launch_bounds__(256) void x_split_kernel(
    const float* __restrict__ x, unsigned short* __restrict__ xh,
    unsigned short* __restrict__ xl)
{
    const int ch = blockIdx.x;
    const int b  = blockIdx.y;
    const int t  = threadIdx.x;
    for (int seg = 0; seg < 16; ++seg) {
        const int n = (seg << 8) + t;
        unsigned short uh[16], ul[16];
#pragma unroll
        for (int c = 0; c < 16; ++c) {
            float f = x[(((size_t)b * 512 + (ch << 4) + c) << 12) + n];
            unsigned short hi = f2bf(f);
            uh[c] = hi;
            ul[c] = f2bf(f - bf2f(hi));
        }
        size_t dst = ((((size_t)b * 32 + ch) << 12) + n) << 4;
        *(uint4*)(xh + dst)     = ((uint4*)uh)[0];
        *(uint4*)(xh + dst + 8) = ((uint4*)uh)[1];
        *(uint4*)(xl + dst)     = ((uint4*)ul)[0];
        *(uint4*)(xl + dst + 8) = ((uint4*)ul)[1];
    }
}

// ---- 3x3 conv + BN + ReLU, bf16 MFMA, blocked input. grid (32, 2, 8) ------
__global__ __launch_bounds__(256) void conv3x3_mfma(
    const unsigned short* __restrict__ xb, int Cin,
    const unsigned short* __restrict__ wpack, const float* __restrict__ bn,
    float* __restrict__ out_f32)
{
    const int t   = threadIdx.x;
    const int w   = t >> 6;
    const int wy  = w >> 1;
    const int wx  = w & 1;
    const int ln  = t & 63;
    const int l31 = ln & 31;
    const int g   = ln >> 5;
    const int y0  = blockIdx.x << 1;
    const int co0 = blockIdx.y << 6;
    const int b   = blockIdx.z;
    const int nc16 = Cin >> 4;

    __shared__ __align__(16) unsigned short Xl[4 * 66 * 16];   // 8448 B
    __shared__ __align__(16) unsigned short Wl[9 * 64 * 16];   // 18432 B

    // zero halo columns once (staging never writes xc 0 / 65)
    if (t < 8) {
        int r = t >> 1, xc = (t & 1) * 65;
        uint4 z = {0, 0, 0, 0};
        *(uint4*)&Xl[(r * 66 + xc) * 16 + 0] = z;
        *(uint4*)&Xl[(r * 66 + xc) * 16 + 8] = z;
    }

    const f32x16 zero = {0,0,0,0,0,0,0,0,0,0,0,0,0,0,0,0};
    f32x16 acc0 = zero, acc1 = zero;

    for (int ch = 0; ch < nc16; ++ch) {
        // X stage: 4 rows x 64 cols x 16 ch, contiguous uint4 loads
#pragma unroll
        for (int it = 0; it < 2; ++it) {
            int idx = t + (it << 8);
            int r = idx >> 7, u = idx & 127;
            int gy = y0 - 1 + r;
            uint4 val = {0, 0, 0, 0};
            if ((unsigned)gy < 64u)
                val = *(const uint4*)(xb + ((((size_t)(b * nc16 + ch)) << 12) + (gy << 6)) * 16 + (u << 3));
            *(uint4*)&Xl[(r * 66 + 1) * 16 + (u << 3)] = val;
        }
        // W stage: 9 taps x 64 co x 16 ci = 1152 uint4
        {
            const uint4* wsrc = (const uint4*)wpack;
            const int base = ch * 2304 + (co0 << 1);
            for (int idx = t; idx < 1152; idx += 256)
                ((uint4*)Wl)[idx] = wsrc[base + ((idx >> 7) << 8) + (idx & 127)];
        }
        __syncthreads();

#pragma unroll 3
        for (int tap = 0; tap < 9; ++tap) {
            const int dy = tap / 3, dx = tap - dy * 3;
            short8 a = *(const short8*)&Wl[((tap << 6) + (wy << 5) + l31) * 16 + (g << 3)];
            const int row = wx + dy;
            short8 b0 = *(const short8*)&Xl[(row * 66 + l31 + dx) * 16 + (g << 3)];
            short8 b1 = *(const short8*)&Xl[(row * 66 + l31 + 32 + dx) * 16 + (g << 3)];
            acc0 = __builtin_amdgcn_mfma_f32_32x32x16_bf16(a, b0, acc0, 0, 0, 0);
            acc1 = __builtin_amdgcn_mfma_f32_32x32x16_bf16(a, b1, acc1, 0, 0, 0);
        }
        __syncthreads();
    }

    const int y = y0 + wx;
#pragma unroll
    for (int j = 0; j < 2; j++) {
        const f32x16 a = j ? acc1 : acc0;
#pragma unroll
        for (int r = 0; r < 16; r++) {
            int co = co0 + (wy << 5) + (r & 3) + ((r >> 2) << 3) + (g << 2);
            int x  = (j << 5) + l31;
            float v = fmaf(a[r], bn[co], bn[128 + co]);
            v = v > 0.f ? v : 0.f;
            out_f32[(((size_t)b * 128 + co) << 12) + (y << 6) + x] = v;
        }
    }
}

// ---- 3x3 conv, hi/lo split MFMA (~fp32), blocked hi/lo inputs -------------
// grid (32, 2, 8). Outputs: fp32 (optional) and/or channel-major bf16 hi/lo.
__global__ __launch_bounds__(256) void conv3x3_mfma_hilo(
    const unsigned short* __restrict__ xbh, const unsigned short* __restrict__ xbl,
    int Cin, const unsigned short* __restrict__ wph, const unsigned short* __restrict__ wpl,
    const float* __restrict__ bn, float* __restrict__ out_f32,
    unsigned short* __restrict__ outh, unsigned short* __restrict__ outl)
{
    const int t   = threadIdx.x;
    const int w   = t >> 6;
    const int wy  = w >> 1;
    const int wx  = w & 1;
    const int ln  = t & 63;
    const int l31 = ln & 31;
    const int g   = ln >> 5;
    const int y0  = blockIdx.x << 1;
    const int co0 = blockIdx.y << 6;
    const int b   = blockIdx.z;
    const int nc16 = Cin >> 4;

    __shared__ __align__(16) unsigned short Xh[4 * 66 * 16];
    __shared__ __align__(16) unsigned short Xo[4 * 66 * 16];
    __shared__ __align__(16) unsigned short Wh[9 * 64 * 16];
    __shared__ __align__(16) unsigned short Wo[9 * 64 * 16];

    if (t < 8) {
        int r = t >> 1, xc = (t & 1) * 65;
        uint4 z = {0, 0, 0, 0};
        *(uint4*)&Xh[(r * 66 + xc) * 16 + 0] = z;
        *(uint4*)&Xh[(r * 66 + xc) * 16 + 8] = z;
        *(uint4*)&Xo[(r * 66 + xc) * 16 + 0] = z;
        *(uint4*)&Xo[(r * 66 + xc) * 16 + 8] = z;
    }

    const f32x16 zero = {0,0,0,0,0,0,0,0,0,0,0,0,0,0,0,0};
    f32x16 acc0 = zero, acc1 = zero;

    for (int ch = 0; ch < nc16; ++ch) {
#pragma unroll
        for (int it = 0; it < 2; ++it) {
            int idx = t + (it << 8);
            int r = idx >> 7, u = idx & 127;
            int gy = y0 - 1 + r;
            uint4 vh = {0, 0, 0, 0}, vl = {0, 0, 0, 0};
            if ((unsigned)gy < 64u) {
                size_t o = ((((size_t)(b * nc16 + ch)) << 12) + (gy << 6)) * 16 + (u << 3);
                vh = *(const uint4*)(xbh + o);
                vl = *(const uint4*)(xbl + o);
            }
            *(uint4*)&Xh[(r * 66 + 1) * 16 + (u << 3)] = vh;
            *(uint4*)&Xo[(r * 66 + 1) * 16 + (u << 3)] = vl;
        }
        {
            const uint4* sh = (const uint4*)wph;
            const uint4* sl = (const uint4*)wpl;
            const int base = ch * 2304 + (co0 << 1);
            for (int idx = t; idx < 1152; idx += 256) {
                int o = base + ((idx >> 7) << 8) + (idx & 127);
                ((uint4*)Wh)[idx] = sh[o];
                ((uint4*)Wo)[idx] = sl[o];
            }
        }
        __syncthreads();

#pragma unroll 1
        for (int tap = 0; tap < 9; ++tap) {
            const int dy = tap / 3, dx = tap - dy * 3;
            const int wi = ((tap << 6) + (wy << 5) + l31) * 16 + (g << 3);
            const int row = wx + dy;
            const int xi0 = (row * 66 + l31 + dx) * 16 + (g << 3);
            const int xi1 = (row * 66 + l31 + 32 + dx) * 16 + (g << 3);
            short8 ah = *(const short8*)&Wh[wi];
            short8 al = *(const short8*)&Wo[wi];
            short8 b0h = *(const short8*)&Xh[xi0];
            short8 b1h = *(const short8*)&Xh[xi1];
            short8 b0l = *(const short8*)&Xo[xi0];
            short8 b1l = *(const short8*)&Xo[xi1];
            acc0 = __builtin_amdgcn_mfma_f32_32x32x16_bf16(ah, b0h, acc0, 0, 0, 0);
            acc1 = __builtin_amdgcn_mfma_f32_32x32x16_bf16(ah, b1h, acc1, 0, 0, 0);
            acc0 = __builtin_amdgcn_mfma_f32_32x32x16_bf16(ah, b0l, acc0, 0, 0, 0);
            acc1 = __builtin_amdgcn_mfma_f32_32x32x16_bf16(ah, b1l, acc1, 0, 0, 0);
            acc0 = __builtin_amdgcn_mfma_f32_32x32x16_bf16(al, b0h, acc0, 0, 0, 0);
            acc1 = __builtin_amdgcn_mfma_f32_32x32x16_bf16(al, b1h, acc1, 0, 0, 0);
        }
        __syncthreads();
    }

    const int y = y0 + wx;
#pragma unroll
    for (int j = 0; j < 2; j++) {
        const f32x16 a = j ? acc1 : acc0;
#pragma unroll
        for (int r = 0; r < 16; r++) {
            int co = co0 + (wy << 5) + (r & 3) + ((r >> 2) << 3) + (g << 2);
            int x  = (j << 5) + l31;
            float v = fmaf(a[r], bn[co], bn[128 + co]);
            v = v > 0.f ? v : 0.f;
            size_t o = (((size_t)b * 128 + co) << 12) + (y << 6) + x;
            if (out_f32) out_f32[o] = v;
            if (outh) {
                unsigned short hi = f2bf(v);
                outh[o] = hi;
                outl[o] = f2bf(v - bf2f(hi));
            }
        }
    }
}

// ---- CAM Gram via hi/lo MFMA, n-split partials. grid (16, 8, 8) -----------
__global__ __launch_bounds__(256) void cam_energy_mfma(
    const unsigned short* __restrict__ bh, const unsigned short* __restrict__ bl,
    float* __restrict__ egy_part)
{
    const int t   = threadIdx.x;
    const int w   = t >> 6;
    const int ln  = t & 63;
    const int l31 = ln & 31;
    const int g   = ln >> 5;
    const int i0  = (blockIdx.x >> 2) << 5;
    const int j0  = (blockIdx.x & 3) << 5;
    const int nseg = blockIdx.y;
    const int b   = blockIdx.z;

    __shared__ float red[4][64][17];

    const f32x16 zero = {0,0,0,0,0,0,0,0,0,0,0,0,0,0,0,0};
    f32x16 acc = zero;
    const int nb = (nseg << 9) + (w << 7) + (g << 3);
    const size_t ri = ((size_t)b * 128 + i0 + l31) << 12;
    const size_t rj = ((size_t)b * 128 + j0 + l31) << 12;

#pragma unroll
    for (int c = 0; c < 8; c++) {
        const int n0 = nb + (c << 4);
        short8 ah  = *(const short8*)(bh + ri + n0);
        short8 al  = *(const short8*)(bl + ri + n0);
        short8 bhf = *(const short8*)(bh + rj + n0);
        short8 blf = *(const short8*)(bl + rj + n0);
        acc = __builtin_amdgcn_mfma_f32_32x32x16_bf16(ah, bhf, acc, 0, 0, 0);
        acc = __builtin_amdgcn_mfma_f32_32x32x16_bf16(ah, blf, acc, 0, 0, 0);
        acc = __builtin_amdgcn_mfma_f32_32x32x16_bf16(al, bhf, acc, 0, 0, 0);
    }
#pragma unroll
    for (int r = 0; r < 16; r++) red[w][ln][r] = acc[r];
    __syncthreads();

    const int lane = t & 63;
    const int rq   = t >> 6;
    float* base = egy_part + (((size_t)(nseg * 8 + b)) << 14);
#pragma unroll
    for (int e = 0; e < 4; e++) {
        const int reg = (rq << 2) + e;
        float v = red[0][lane][reg] + red[1][lane][reg]
                + red[2][lane][reg] + red[3][lane][reg];
        const int i = i0 + (reg & 3) + ((reg >> 2) << 3) + ((lane >> 5) << 2);
        base[i * 128 + j0 + (lane & 31)] = v;
    }
}

// ---- CAM softmax of (rowmax - e), fused 8-seg reduce. grid (8, 8) ---------
__global__ __launch_bounds__(256) void cam_softmax_fused(
    const float* __restrict__ egy_part, float* __restrict__ egy)
{
    const int b   = blockIdx.x;
    const int rg  = blockIdx.y;
    const int t   = threadIdx.x;
    const int row = (rg << 4) + (t >> 4);
    const int jg  = t & 15;

    float e[8];
#pragma unroll
    for (int jj = 0; jj < 8; jj++) e[jj] = 0.f;
    for (int seg = 0; seg < 8; seg++) {
        const float* p = egy_part + (((size_t)(seg * 8 + b)) << 14) + row * 128 + (jg << 3);
#pragma unroll
        for (int jj = 0; jj < 8; jj++) e[jj] += p[jj];
    }
    float mn = e[0];
#pragma unroll
    for (int jj = 1; jj < 8; jj++) mn = fminf(mn, e[jj]);
#pragma unroll
    for (int k = 1; k < 16; k <<= 1) mn = fminf(mn, __shfl_xor(mn, k));
    float s = 0.f;
#pragma unroll
    for (int jj = 0; jj < 8; jj++) { float p = __expf(mn - e[jj]); e[jj] = p; s += p; }
#pragma unroll
    for (int k = 1; k < 16; k <<= 1) s += __shfl_xor(s, k);
    const float inv = 1.f / s;
    float* orow = egy + ((size_t)b << 14) + row * 128 + (jg << 3);
#pragma unroll
    for (int jj = 0; jj < 8; jj++) orow[jj] = e[jj] * inv;
}

// ---- PAM Q/K producer ----
__global__ __launch_bounds__(256) void pam_qk_1x1(
    const float* __restrict__ A, const float* __restrict__ Wb, const float* __restrict__ bb,
    const float* __restrict__ Wc, const float* __restrict__ bc,
    unsigned short* __restrict__ qt, unsigned short* __restrict__ kt)
{
    __shared__ float wl[2 * 16 * 128];
    __shared__ float bl[32];
    const int t = threadIdx.x;
    const int n = (blockIdx.x << 8) + t;
    const int b = blockIdx.y;
    for (int idx = t; idx < 2048; idx += 256) { wl[idx] = Wb[idx]; wl[2048 + idx] = Wc[idx]; }
    if (t < 16) { bl[t] = bb[t]; bl[16 + t] = bc[t]; }
    __syncthreads();
    float ab[16], ac[16];
#pragma unroll
    for (int k = 0; k < 16; k++) { ab[k] = 0.f; ac[k] = 0.f; }
    for (int chn = 0; chn < 128; ++chn) {
        float a = A[(((size_t)b * 128 + chn) << 12) + n];
#pragma unroll
        for (int k = 0; k < 16; k++) {
            ab[k] = fmaf(wl[k * 128 + chn], a, ab[k]);
            ac[k] = fmaf(wl[2048 + k * 128 + chn], a, ac[k]);
        }
    }
    unsigned short uq[16], uk[16];
#pragma unroll
    for (int k = 0; k < 16; k++) {
        uq[k] = f2bf(ab[k] + bl[k]);
        uk[k] = f2bf(ac[k] + bl[16 + k]);
    }
    size_t row = (size_t)b * 4096 + n;
    ((uint4*)qt)[row * 2 + 0] = ((uint4*)uq)[0];
    ((uint4*)qt)[row * 2 + 1] = ((uint4*)uq)[1];
    ((uint4*)kt)[row * 2 + 0] = ((uint4*)uk)[0];
    ((uint4*)kt)[row * 2 + 1] = ((uint4*)uk)[1];
}

// ---- PAM V producer ----
__global__ __launch_bounds__(256) void pam_v_1x1(
    const float* __restrict__ A, const float* __restrict__ Wd, const float* __restrict__ bd,
    unsigned short* __restrict__ vb)
{
    __shared__ float wl[32 * 128];
    __shared__ float bl[32];
    const int t   = threadIdx.x;
    const int n   = (blockIdx.x << 8) + t;
    const int co0 = blockIdx.y << 5;
    const int b   = blockIdx.z;
    for (int idx = t; idx < 4096; idx += 256) {
        int c2 = idx >> 7, chv = idx & 127;
        wl[idx] = Wd[(co0 + c2) * 128 + chv];
    }
    if (t < 32) bl[t] = bd[co0 + t];
    __syncthreads();
    float acc[32];
#pragma unroll
    for (int k = 0; k < 32; k++) acc[k] = 0.f;
    for (int chn = 0; chn < 128; ++chn) {
        float a = A[(((size_t)b * 128 + chn) << 12) + n];
#pragma unroll
        for (int k = 0; k < 32; k++) acc[k] = fmaf(wl[k * 128 + chn], a, acc[k]);
    }
#pragma unroll
    for (int k = 0; k < 32; k++)
        vb[(((size_t)b * 128 + co0 + k) << 12) + n] = f2bf(acc[k] + bl[k]);
}

// ---- PAM rowmax ----
__global__ __launch_bounds__(256) void pam_rowmax(
    const unsigned short* __restrict__ qt, const unsigned short* __restrict__ kt,
    float* __restrict__ rowmax)
{
    const int t  = threadIdx.x;
    const int w  = t >> 6;
    const int L  = t & 63;
    const int ln = L & 31;
    const int g  = L >> 5;
    const int b  = blockIdx.y;
    const int n0 = blockIdx.x << 5;
    __shared__ float red[4][32];

    const f32x16 zero = {0,0,0,0,0,0,0,0,0,0,0,0,0,0,0,0};
    short8 qfrag = *(const short8*)(qt + (((size_t)b * 4096 + n0 + ln) << 4) + (g << 3));

    float mx = -INFINITY;
    for (int mq = (w << 5); mq < 4096; mq += 128) {
        short8 kfrag = *(const short8*)(kt + (((size_t)b * 4096 + mq + ln) << 4) + (g << 3));
        f32x16 s = __builtin_amdgcn_mfma_f32_32x32x16_bf16(kfrag, qfrag, zero, 0, 0, 0);
#pragma unroll
        for (int r = 0; r < 16; r++) mx = fmaxf(mx, s[r]);
    }
    mx = fmaxf(mx, __shfl_xor(mx, 32));
    if (L < 32) red[w][L] = mx;
    __syncthreads();
    if (t < 32) {
        float m = fmaxf(fmaxf(red[0][t], red[1][t]), fmaxf(red[2][t], red[3][t]));
        rowmax[((size_t)b << 12) + n0 + t] = m;
    }
}

// ---- PAM attention, MFMA; out = blocked bf16 [b][8][4096][16] -------------
__global__ __launch_bounds__(256) void pam_attn_mfma(
    const unsigned short* __restrict__ qt, const unsigned short* __restrict__ kt,
    const unsigned short* __restrict__ vb, const float* __restrict__ rowmax,
    const float* __restrict__ alpha, const float* __restrict__ Y,
    unsigned short* __restrict__ outb)
{
    const int t  = threadIdx.x;
    const int w  = t >> 6;
    const int L  = t & 63;
    const int ln = L & 31;
    const int g  = L >> 5;
    const int b  = blockIdx.y;
    const int n0 = blockIdx.x << 5;
    const int c0 = w << 5;

    __shared__ unsigned short Pf[16 * 256];
    __shared__ float red[4][32];

    const f32x16 zero = {0,0,0,0,0,0,0,0,0,0,0,0,0,0,0,0};
    short8 qfrag = *(const short8*)(qt + (((size_t)b * 4096 + n0 + ln) << 4) + (g << 3));
    const float rm = rowmax[((size_t)b << 12) + n0 + ln];
    const float al = alpha[0];

    f32x16 acc = zero;
    float rs = 0.f;

    for (int m0 = 0; m0 < 4096; m0 += 128) {
        const int mq = m0 + (w << 5);
        short8 kfrag = *(const short8*)(kt + (((size_t)b * 4096 + mq + ln) << 4) + (g << 3));
        f32x16 s = __builtin_amdgcn_mfma_f32_32x32x16_bf16(kfrag, qfrag, zero, 0, 0, 0);

        float p[16];
#pragma unroll
        for (int r = 0; r < 16; r++) { p[r] = __expf(s[r] - rm); rs += p[r]; }
        float xx[16];
#pragma unroll
        for (int r = 0; r < 16; r++) xx[r] = __shfl_xor(p[r], 32);

        unsigned short f0[8], f1[8];
#pragma unroll
        for (int i = 0; i < 4; i++) {
            f0[i]     = f2bf(g ? xx[4 + i]  : p[i]);
            f0[4 + i] = f2bf(g ? p[4 + i]   : xx[i]);
            f1[i]     = f2bf(g ? xx[12 + i] : p[8 + i]);
            f1[4 + i] = f2bf(g ? p[12 + i]  : xx[8 + i]);
        }
        *(short8*)(&Pf[((w << 2) + g) * 256 + (ln << 3)])     = *(short8*)f0;
        *(short8*)(&Pf[((w << 2) + 2 + g) * 256 + (ln << 3)]) = *(short8*)f1;
        __syncthreads();

#pragma unroll
        for (int kk = 0; kk < 8; kk++) {
            short8 pfrag = *(const short8*)(&Pf[((kk << 1) + g) * 256 + (ln << 3)]);
            short8 vfrag = *(const short8*)(vb + (((size_t)b * 128 + c0 + ln) << 12)
                                               + m0 + (kk << 4) + (g << 3));
            acc = __builtin_amdgcn_mfma_f32_32x32x16_bf16(vfrag, pfrag, acc, 0, 0, 0);
        }
        __syncthreads();
    }

    rs += __shfl_xor(rs, 32);
    if (L < 32) red[w][L] = rs;
    __syncthreads();
    const float inv = 1.f / (red[0][ln] + red[1][ln] + red[2][ln] + red[3][ln]);
    const int n = n0 + ln;
#pragma unroll
    for (int r = 0; r < 16; r++) {
        int c = c0 + (r & 3) + ((r >> 2) << 3) + (g << 2);
        size_t yi = (((size_t)b * 128 + c) << 12) + n;
        size_t oo = ((((size_t)b * 8 + (c >> 4)) << 12) + n) * 16 + (c & 15);
        outb[oo] = f2bf(fmaf(al, acc[r] * inv, Y[yi]));
    }
}

// ---- CAM feat: in = bh/blo (channel-major), out = blocked hi/lo bf16 ------
__global__ __launch_bounds__(256) void cam_feat(
    const float* __restrict__ attn, const unsigned short* __restrict__ bh,
    const unsigned short* __restrict__ blo, const float* __restrict__ beta,
    unsigned short* __restrict__ camh, unsigned short* __restrict__ caml)
{
    const int t  = threadIdx.x;
    const int n  = (blockIdx.x << 8) + t;
    const int c0 = blockIdx.y << 5;
    const int b  = blockIdx.z;
    __shared__ float al[32 * 128];
    for (int idx = t; idx < 4096; idx += 256)
        al[idx] = attn[((size_t)b << 14) + (c0 + (idx >> 7)) * 128 + (idx & 127)];
    __syncthreads();
    float acc[32];
#pragma unroll
    for (int k = 0; k < 32; k++) acc[k] = 0.f;
    for (int d = 0; d < 128; ++d) {
        size_t idx = (((size_t)b * 128 + d) << 12) + n;
        float v = bf2f(bh[idx]) + bf2f(blo[idx]);
#pragma unroll
        for (int k = 0; k < 32; k++) acc[k] = fmaf(al[k * 128 + d], v, acc[k]);
    }
    float be = beta[0];
    unsigned short oh[32], ol[32];
#pragma unroll
    for (int k = 0; k < 32; k++) {
        size_t idx = (((size_t)b * 128 + c0 + k) << 12) + n;
        float bfv = bf2f(bh[idx]) + bf2f(blo[idx]);
        float v = fmaf(be, acc[k], bfv);
        unsigned short hi = f2bf(v);
        oh[k] = hi;
        ol[k] = f2bf(v - bf2f(hi));
    }
    const int g0 = c0 >> 4;
    size_t d0 = ((((size_t)b * 8 + g0) << 12) + n) << 4;
    size_t d1 = ((((size_t)b * 8 + g0 + 1) << 12) + n) << 4;
    *(uint4*)(camh + d0)     = ((uint4*)oh)[0];
    *(uint4*)(camh + d0 + 8) = ((uint4*)oh)[1];
    *(uint4*)(camh + d1)     = ((uint4*)oh)[2];
    *(uint4*)(camh + d1 + 8) = ((uint4*)oh)[3];
    *(uint4*)(caml + d0)     = ((uint4*)ol)[0];
    *(uint4*)(caml + d0 + 8) = ((uint4*)ol)[1];
    *(uint4*)(caml + d1)     = ((uint4*)ol)[2];
    *(uint4*)(caml + d1 + 8) = ((uint4*)ol)[3];
}

// ---- Final heads ----
__global__ __launch_bounds__(256) void heads(
    const float* __restrict__ FP, const float* __restrict__ FC,
    const float* __restrict__ Wout, const float* __restrict__ bout,
    const float* __restrict__ Wp3, const float* __restrict__ bp3,
    const float* __restrict__ Wc3, const float* __restrict__ bc3,
    float* __restrict__ out)
{
    const int t = threadIdx.x;
    const int n = (blockIdx.x << 8) + t;
    const int b = blockIdx.y;
    __shared__ float wl[3 * 19 * 128];
    __shared__ float bl[3 * 19];
    for (int idx = t; idx < 2432; idx += 256) {
        wl[idx]        = Wout[idx];
        wl[2432 + idx] = Wp3[idx];
        wl[4864 + idx] = Wc3[idx];
    }
    if (t < 19) { bl[t] = bout[t]; bl[19 + t] = bp3[t]; bl[38 + t] = bc3[t]; }
    __syncthreads();
    float am[19], ap[19], ac[19];
#pragma unroll
    for (int o = 0; o < 19; o++) { am[o] = 0.f; ap[o] = 0.f; ac[o] = 0.f; }
    for (int chn = 0; chn < 128; ++chn) {
        float pv = FP[(((size_t)b * 128 + chn) << 12) + n];
        float cv = FC[(((size_t)b * 128 + chn) << 12) + n];
        float fv = pv + cv;
#pragma unroll
        for (int o = 0; o < 19; o++) {
            am[o] = fmaf(wl[o * 128 + chn], fv, am[o]);
            ap[o] = fmaf(wl[2432 + o * 128 + chn], pv, ap[o]);
            ac[o] = fmaf(wl[4864 + o * 128 + chn], cv, ac[o]);
        }
    }
    const size_t OS = (size_t)8 * 19 * 4096;
#pragma unroll
    for (int o = 0; o < 19; o++) {
        size_t base = (((size_t)b * 19 + o) << 12) + n;
        out[base]          = 1.f / (1.f + __expf(-(am[o] + bl[o])));
        out[OS + base]     = 1.f / (1.f + __expf(-(ap[o] + bl[19 + o])));
        out[2 * OS + base] = 1.f / (1.f + __expf(-(ac[o] + bl[38 + o])));
    }
}

extern "C" void kernel_launch(void* const* d_in, const int* in_sizes, int n_in,
                              void* d_out, int out_size, void* d_ws, size_t ws_size,
                              hipStream_t stream)
{
    const float* x     = (const float*)d_in[0];
    const float* Wp1   = (const float*)d_in[1];
    const float* bnp1  = (const float*)d_in[2];
    const float* Wc1   = (const float*)d_in[3];
    const float* bnc1  = (const float*)d_in[4];
    const float* Wb    = (const float*)d_in[5];
    const float* bb    = (const float*)d_in[6];
    const float* Wc    = (const float*)d_in[7];
    const float* bcv   = (const float*)d_in[8];
    const float* Wd    = (const float*)d_in[9];
    const float* bd    = (const float*)d_in[10];
    const float* alpha = (const float*)d_in[11];
    const float* beta  = (const float*)d_in[12];
    const float* Wp2   = (const float*)d_in[13];
    const float* bnp2  = (const float*)d_in[14];
    const float* Wc2   = (const float*)d_in[15];
    const float* bnc2  = (const float*)d_in[16];
    const float* Wout  = (const float*)d_in[17];
    const float* bo    = (const float*)d_in[18];
    const float* Wp3   = (const float*)d_in[19];
    const float* bp3   = (const float*)d_in[20];
    const float* Wc3   = (const float*)d_in[21];
    const float* bc3   = (const float*)d_in[22];
    float* out = (float*)d_out;

    char* ws = (char*)d_ws;
    const size_t MB = 1u << 20;
    const size_t W1SZ = (size_t)32 * 18432 * 2;   // 1.125 MB
    const size_t W2SZ = (size_t)8 * 18432 * 2;    // 288 KB
    float*          bufA     = (float*)(ws);                     // conv1p out -> conv2c out
    unsigned short* bh       = (unsigned short*)(ws + 16 * MB);  // conv1c hi
    unsigned short* blo      = (unsigned short*)(ws + 24 * MB);  // conv1c lo
    unsigned short* xh       = (unsigned short*)(ws + 32 * MB);  // 32MB (dead after conv1c)
    unsigned short* xl       = (unsigned short*)(ws + 64 * MB);  // 32MB (dead after conv1c)
    float*          egy_part = (float*)(ws + 32 * MB);           // 4MB
    unsigned short* qt       = (unsigned short*)(ws + 36 * MB);
    unsigned short* kt       = (unsigned short*)(ws + 37 * MB);
    float*          rowmax   = (float*)(ws + 38 * MB);
    float*          egy      = (float*)(ws + 38 * MB + (1u << 18));
    unsigned short* vb       = (unsigned short*)(ws + 40 * MB);  // 8MB
    float*          bufD     = (float*)(ws + 48 * MB);           // 16MB conv2p out
    unsigned short* pam_bfB  = (unsigned short*)(ws + 64 * MB);  // 8MB blocked
    unsigned short* camh     = (unsigned short*)(ws + 72 * MB);  // 8MB blocked
    unsigned short* caml     = (unsigned short*)(ws + 80 * MB);  // 8MB blocked
    unsigned short* wp1      = (unsigned short*)(ws + 96 * MB);
    unsigned short* wc1h     = (unsigned short*)(ws + 96 * MB + W1SZ);
    unsigned short* wc1l     = (unsigned short*)(ws + 96 * MB + 2 * W1SZ);
    unsigned short* wp2      = (unsigned short*)(ws + 96 * MB + 3 * W1SZ);
    unsigned short* wc2h     = (unsigned short*)(ws + 96 * MB + 3 * W1SZ + W2SZ);
    unsigned short* wc2l     = (unsigned short*)(ws + 96 * MB + 3 * W1SZ + 2 * W2SZ);

    dim3 blk(256);
    const int n1 = 32 * 18432;
    const int n2 = 8 * 18432;
    wpack_kernel<<<dim3((n1 + 255) / 256), blk, 0, stream>>>(Wp1, wp1, 512, n1);
    wpack_kernel<<<dim3((n2 + 255) / 256), blk, 0, stream>>>(Wp2, wp2, 128, n2);
    wpack_split_kernel<<<dim3((n1 + 255) / 256), blk, 0, stream>>>(Wc1, wc1h, wc1l, 512, n1);
    wpack_split_kernel<<<dim3((n2 + 255) / 256), blk, 0, stream>>>(Wc2, wc2h, wc2l, 128, n2);

    // input split/transpose to blocked bf16
    x_split_kernel<<<dim3(32, 8), blk, 0, stream>>>(x, xh, xl);

    // conv1p (plain) and conv1c (hilo -> bh/blo only)
    conv3x3_mfma<<<dim3(32, 2, 8), blk, 0, stream>>>(xh, 512, wp1, bnp1, bufA);
    conv3x3_mfma_hilo<<<dim3(32, 2, 8), blk, 0, stream>>>(xh, xl, 512, wc1h, wc1l, bnc1,
                                                          (float*)0, bh, blo);
    // CAM Gram + softmax
    cam_energy_mfma<<<dim3(16, 8, 8), blk, 0, stream>>>(bh, blo, egy_part);
    cam_softmax_fused<<<dim3(8, 8), blk, 0, stream>>>(egy_part, egy);
    // PAM
    pam_qk_1x1<<<dim3(16, 8), blk, 0, stream>>>(bufA, Wb, bb, Wc, bcv, qt, kt);
    pam_v_1x1<<<dim3(16, 4, 8), blk, 0, stream>>>(bufA, Wd, bd, vb);
    pam_rowmax<<<dim3(128, 8), blk, 0, stream>>>(qt, kt, rowmax);
    pam_attn_mfma<<<dim3(128, 8), blk, 0, stream>>>(qt, kt, vb, rowmax, alpha, bufA, pam_bfB);
    // conv2p
    conv3x3_mfma<<<dim3(32, 2, 8), blk, 0, stream>>>(pam_bfB, 128, wp2, bnp2, bufD);
    // CAM tail
    cam_feat<<<dim3(16, 4, 8), blk, 0, stream>>>(egy, bh, blo, beta, camh, caml);
    conv3x3_mfma_hilo<<<dim3(32, 2, 8), blk, 0, stream>>>(camh, caml, 128, wc2h, wc2l, bnc2,
                                                          bufA, (unsigned short*)0, (unsigned short*)0);
    // fusion + heads
    heads<<<dim3(16, 8), blk, 0, stream>>>(bufD, bufA, Wout, bo, Wp3, bp3, Wc3, bc3, out);
}

// Round 8
// 866.197 us; speedup vs baseline: 1.0314x; 1.0314x over previous
//
#include <hip/hip_runtime.h>
#include <math.h>

// ---------------------------------------------------------------------------
// DAHead: B=8, Cin=512, Ci=128, H=W=64, N=4096, Ck=16, NC=19.
// R8: R7 (m-blocked V + m-split PAM + combine) with the ws aliasing fix:
//     weights live at 96M, OUTSIDE xl's 64..96M span (R7 clobbered them).
// ws (byte offsets):
//   bufA@0(16M) bh@16M blo@24M | xh@32M(32M) xl@64M(32M) [dead after conv1c]
//   then: egy_part@32M(4M) qt@36M kt@37M rowmax@38M egy@38.125M vbB@39M(8M)
//   part@47M(32M: two 16M halves) lsum@79M(256K) pam_bfB@80M(8M)
//   after combine: bufD@47M(16M) camh@63M caml@71M | weights@96M(~4.3M)
// ---------------------------------------------------------------------------

typedef __attribute__((ext_vector_type(8)))  short short8;
typedef __attribute__((ext_vector_type(16))) float f32x16;

__device__ inline unsigned short f2bf(float f) {
    union { float f; unsigned u; } v; v.f = f;
    unsigned r = v.u + 0x7fffu + ((v.u >> 16) & 1u);   // RNE
    return (unsigned short)(r >> 16);
}
__device__ inline float bf2f(unsigned short h) {
    union { unsigned u; float f; } v; v.u = ((unsigned)h) << 16;
    return v.f;
}

// ---- weight prepack: W[co][cin][9] fp32 -> wpack[chunk][tap][co128][16] ---
__global__ __launch_bounds__(256) void wpack_kernel(
    const float* __restrict__ W, unsigned short* __restrict__ wp, int Cin, int total)
{
    int idx = blockIdx.x * 256 + threadIdx.x;
    if (idx >= total) return;
    int chunk = idx / 18432;
    int rem   = idx - chunk * 18432;
    int tap   = rem >> 11;
    int rem2  = rem & 2047;
    int co    = rem2 >> 4;
    int ci    = rem2 & 15;
    int cin   = (chunk << 4) + ci;
    wp[idx] = f2bf(W[((size_t)co * Cin + cin) * 9 + tap]);
}

__global__ __launch_bounds__(256) void wpack_split_kernel(
    const float* __restrict__ W, unsigned short* __restrict__ wph,
    unsigned short* __restrict__ wpl, int Cin, int total)
{
    int idx = blockIdx.x * 256 + threadIdx.x;
    if (idx >= total) return;
    int chunk = idx / 18432;
    int rem   = idx - chunk * 18432;
    int tap   = rem >> 11;
    int rem2  = rem & 2047;
    int co    = rem2 >> 4;
    int ci    = rem2 & 15;
    int cin   = (chunk << 4) + ci;
    float w = W[((size_t)co * Cin + cin) * 9 + tap];
    unsigned short hi = f2bf(w);
    wph[idx] = hi;
    wpl[idx] = f2bf(w - bf2f(hi));
}

// ---- x split+transpose: x fp32 [b][512][4096] -> xh/xl blocked bf16 -------
__global__ __launch_bounds__(256) void x_split_kernel(
    const float* __restrict__ x, unsigned short* __restrict__ xh,
    unsigned short* __restrict__ xl)
{
    const int ch = blockIdx.x;
    const int b  = blockIdx.y;
    const int t  = threadIdx.x;
    for (int seg = 0; seg < 16; ++seg) {
        const int n = (seg << 8) + t;
        unsigned short uh[16], ul[16];
#pragma unroll
        for (int c = 0; c < 16; ++c) {
            float f = x[(((size_t)b * 512 + (ch << 4) + c) << 12) + n];
            unsigned short hi = f2bf(f);
            uh[c] = hi;
            ul[c] = f2bf(f - bf2f(hi));
        }
        size_t dst = ((((size_t)b * 32 + ch) << 12) + n) << 4;
        *(uint4*)(xh + dst)     = ((uint4*)uh)[0];
        *(uint4*)(xh + dst + 8) = ((uint4*)uh)[1];
        *(uint4*)(xl + dst)     = ((uint4*)ul)[0];
        *(uint4*)(xl + dst + 8) = ((uint4*)ul)[1];
    }
}

// ---- 3x3 conv + BN + ReLU, bf16 MFMA, blocked input. grid (32, 2, 8) ------
__global__ __launch_bounds__(256) void conv3x3_mfma(
    const unsigned short* __restrict__ xb, int Cin,
    const unsigned short* __restrict__ wpack, const float* __restrict__ bn,
    float* __restrict__ out_f32)
{
    const int t   = threadIdx.x;
    const int w   = t >> 6;
    const int wy  = w >> 1;
    const int wx  = w & 1;
    const int ln  = t & 63;
    const int l31 = ln & 31;
    const int g   = ln >> 5;
    const int y0  = blockIdx.x << 1;
    const int co0 = blockIdx.y << 6;
    const int b   = blockIdx.z;
    const int nc16 = Cin >> 4;

    __shared__ __align__(16) unsigned short Xl[4 * 66 * 16];
    __shared__ __align__(16) unsigned short Wl[9 * 64 * 16];

    if (t < 8) {
        int r = t >> 1, xc = (t & 1) * 65;
        uint4 z = {0, 0, 0, 0};
        *(uint4*)&Xl[(r * 66 + xc) * 16 + 0] = z;
        *(uint4*)&Xl[(r * 66 + xc) * 16 + 8] = z;
    }

    const f32x16 zero = {0,0,0,0,0,0,0,0,0,0,0,0,0,0,0,0};
    f32x16 acc0 = zero, acc1 = zero;

    for (int ch = 0; ch < nc16; ++ch) {
#pragma unroll
        for (int it = 0; it < 2; ++it) {
            int idx = t + (it << 8);
            int r = idx >> 7, u = idx & 127;
            int gy = y0 - 1 + r;
            uint4 val = {0, 0, 0, 0};
            if ((unsigned)gy < 64u)
                val = *(const uint4*)(xb + ((((size_t)(b * nc16 + ch)) << 12) + (gy << 6)) * 16 + (u << 3));
            *(uint4*)&Xl[(r * 66 + 1) * 16 + (u << 3)] = val;
        }
        {
            const uint4* wsrc = (const uint4*)wpack;
            const int base = ch * 2304 + (co0 << 1);
            for (int idx = t; idx < 1152; idx += 256)
                ((uint4*)Wl)[idx] = wsrc[base + ((idx >> 7) << 8) + (idx & 127)];
        }
        __syncthreads();

#pragma unroll 3
        for (int tap = 0; tap < 9; ++tap) {
            const int dy = tap / 3, dx = tap - dy * 3;
            short8 a = *(const short8*)&Wl[((tap << 6) + (wy << 5) + l31) * 16 + (g << 3)];
            const int row = wx + dy;
            short8 b0 = *(const short8*)&Xl[(row * 66 + l31 + dx) * 16 + (g << 3)];
            short8 b1 = *(const short8*)&Xl[(row * 66 + l31 + 32 + dx) * 16 + (g << 3)];
            acc0 = __builtin_amdgcn_mfma_f32_32x32x16_bf16(a, b0, acc0, 0, 0, 0);
            acc1 = __builtin_amdgcn_mfma_f32_32x32x16_bf16(a, b1, acc1, 0, 0, 0);
        }
        __syncthreads();
    }

    const int y = y0 + wx;
#pragma unroll
    for (int j = 0; j < 2; j++) {
        const f32x16 a = j ? acc1 : acc0;
#pragma unroll
        for (int r = 0; r < 16; r++) {
            int co = co0 + (wy << 5) + (r & 3) + ((r >> 2) << 3) + (g << 2);
            int x  = (j << 5) + l31;
            float v = fmaf(a[r], bn[co], bn[128 + co]);
            v = v > 0.f ? v : 0.f;
            out_f32[(((size_t)b * 128 + co) << 12) + (y << 6) + x] = v;
        }
    }
}

// ---- 3x3 conv, hi/lo split MFMA (~fp32), blocked hi/lo inputs -------------
__global__ __launch_bounds__(256) void conv3x3_mfma_hilo(
    const unsigned short* __restrict__ xbh, const unsigned short* __restrict__ xbl,
    int Cin, const unsigned short* __restrict__ wph, const unsigned short* __restrict__ wpl,
    const float* __restrict__ bn, float* __restrict__ out_f32,
    unsigned short* __restrict__ outh, unsigned short* __restrict__ outl)
{
    const int t   = threadIdx.x;
    const int w   = t >> 6;
    const int wy  = w >> 1;
    const int wx  = w & 1;
    const int ln  = t & 63;
    const int l31 = ln & 31;
    const int g   = ln >> 5;
    const int y0  = blockIdx.x << 1;
    const int co0 = blockIdx.y << 6;
    const int b   = blockIdx.z;
    const int nc16 = Cin >> 4;

    __shared__ __align__(16) unsigned short Xh[4 * 66 * 16];
    __shared__ __align__(16) unsigned short Xo[4 * 66 * 16];
    __shared__ __align__(16) unsigned short Wh[9 * 64 * 16];
    __shared__ __align__(16) unsigned short Wo[9 * 64 * 16];

    if (t < 8) {
        int r = t >> 1, xc = (t & 1) * 65;
        uint4 z = {0, 0, 0, 0};
        *(uint4*)&Xh[(r * 66 + xc) * 16 + 0] = z;
        *(uint4*)&Xh[(r * 66 + xc) * 16 + 8] = z;
        *(uint4*)&Xo[(r * 66 + xc) * 16 + 0] = z;
        *(uint4*)&Xo[(r * 66 + xc) * 16 + 8] = z;
    }

    const f32x16 zero = {0,0,0,0,0,0,0,0,0,0,0,0,0,0,0,0};
    f32x16 acc0 = zero, acc1 = zero;

    for (int ch = 0; ch < nc16; ++ch) {
#pragma unroll
        for (int it = 0; it < 2; ++it) {
            int idx = t + (it << 8);
            int r = idx >> 7, u = idx & 127;
            int gy = y0 - 1 + r;
            uint4 vh = {0, 0, 0, 0}, vl = {0, 0, 0, 0};
            if ((unsigned)gy < 64u) {
                size_t o = ((((size_t)(b * nc16 + ch)) << 12) + (gy << 6)) * 16 + (u << 3);
                vh = *(const uint4*)(xbh + o);
                vl = *(const uint4*)(xbl + o);
            }
            *(uint4*)&Xh[(r * 66 + 1) * 16 + (u << 3)] = vh;
            *(uint4*)&Xo[(r * 66 + 1) * 16 + (u << 3)] = vl;
        }
        {
            const uint4* sh = (const uint4*)wph;
            const uint4* sl = (const uint4*)wpl;
            const int base = ch * 2304 + (co0 << 1);
            for (int idx = t; idx < 1152; idx += 256) {
                int o = base + ((idx >> 7) << 8) + (idx & 127);
                ((uint4*)Wh)[idx] = sh[o];
                ((uint4*)Wo)[idx] = sl[o];
            }
        }
        __syncthreads();

#pragma unroll 1
        for (int tap = 0; tap < 9; ++tap) {
            const int dy = tap / 3, dx = tap - dy * 3;
            const int wi = ((tap << 6) + (wy << 5) + l31) * 16 + (g << 3);
            const int row = wx + dy;
            const int xi0 = (row * 66 + l31 + dx) * 16 + (g << 3);
            const int xi1 = (row * 66 + l31 + 32 + dx) * 16 + (g << 3);
            short8 ah = *(const short8*)&Wh[wi];
            short8 al = *(const short8*)&Wo[wi];
            short8 b0h = *(const short8*)&Xh[xi0];
            short8 b1h = *(const short8*)&Xh[xi1];
            short8 b0l = *(const short8*)&Xo[xi0];
            short8 b1l = *(const short8*)&Xo[xi1];
            acc0 = __builtin_amdgcn_mfma_f32_32x32x16_bf16(ah, b0h, acc0, 0, 0, 0);
            acc1 = __builtin_amdgcn_mfma_f32_32x32x16_bf16(ah, b1h, acc1, 0, 0, 0);
            acc0 = __builtin_amdgcn_mfma_f32_32x32x16_bf16(ah, b0l, acc0, 0, 0, 0);
            acc1 = __builtin_amdgcn_mfma_f32_32x32x16_bf16(ah, b1l, acc1, 0, 0, 0);
            acc0 = __builtin_amdgcn_mfma_f32_32x32x16_bf16(al, b0h, acc0, 0, 0, 0);
            acc1 = __builtin_amdgcn_mfma_f32_32x32x16_bf16(al, b1h, acc1, 0, 0, 0);
        }
        __syncthreads();
    }

    const int y = y0 + wx;
#pragma unroll
    for (int j = 0; j < 2; j++) {
        const f32x16 a = j ? acc1 : acc0;
#pragma unroll
        for (int r = 0; r < 16; r++) {
            int co = co0 + (wy << 5) + (r & 3) + ((r >> 2) << 3) + (g << 2);
            int x  = (j << 5) + l31;
            float v = fmaf(a[r], bn[co], bn[128 + co]);
            v = v > 0.f ? v : 0.f;
            size_t o = (((size_t)b * 128 + co) << 12) + (y << 6) + x;
            if (out_f32) out_f32[o] = v;
            if (outh) {
                unsigned short hi = f2bf(v);
                outh[o] = hi;
                outl[o] = f2bf(v - bf2f(hi));
            }
        }
    }
}

// ---- CAM Gram via hi/lo MFMA, n-split partials. grid (16, 8, 8) -----------
__global__ __launch_bounds__(256) void cam_energy_mfma(
    const unsigned short* __restrict__ bh, const unsigned short* __restrict__ bl,
    float* __restrict__ egy_part)
{
    const int t   = threadIdx.x;
    const int w   = t >> 6;
    const int ln  = t & 63;
    const int l31 = ln & 31;
    const int g   = ln >> 5;
    const int i0  = (blockIdx.x >> 2) << 5;
    const int j0  = (blockIdx.x & 3) << 5;
    const int nseg = blockIdx.y;
    const int b   = blockIdx.z;

    __shared__ float red[4][64][17];

    const f32x16 zero = {0,0,0,0,0,0,0,0,0,0,0,0,0,0,0,0};
    f32x16 acc = zero;
    const int nb = (nseg << 9) + (w << 7) + (g << 3);
    const size_t ri = ((size_t)b * 128 + i0 + l31) << 12;
    const size_t rj = ((size_t)b * 128 + j0 + l31) << 12;

#pragma unroll
    for (int c = 0; c < 8; c++) {
        const int n0 = nb + (c << 4);
        short8 ah  = *(const short8*)(bh + ri + n0);
        short8 al  = *(const short8*)(bl + ri + n0);
        short8 bhf = *(const short8*)(bh + rj + n0);
        short8 blf = *(const short8*)(bl + rj + n0);
        acc = __builtin_amdgcn_mfma_f32_32x32x16_bf16(ah, bhf, acc, 0, 0, 0);
        acc = __builtin_amdgcn_mfma_f32_32x32x16_bf16(ah, blf, acc, 0, 0, 0);
        acc = __builtin_amdgcn_mfma_f32_32x32x16_bf16(al, bhf, acc, 0, 0, 0);
    }
#pragma unroll
    for (int r = 0; r < 16; r++) red[w][ln][r] = acc[r];
    __syncthreads();

    const int lane = t & 63;
    const int rq   = t >> 6;
    float* base = egy_part + (((size_t)(nseg * 8 + b)) << 14);
#pragma unroll
    for (int e = 0; e < 4; e++) {
        const int reg = (rq << 2) + e;
        float v = red[0][lane][reg] + red[1][lane][reg]
                + red[2][lane][reg] + red[3][lane][reg];
        const int i = i0 + (reg & 3) + ((reg >> 2) << 3) + ((lane >> 5) << 2);
        base[i * 128 + j0 + (lane & 31)] = v;
    }
}

// ---- CAM softmax of (rowmax - e), fused 8-seg reduce. grid (8, 8) ---------
__global__ __launch_bounds__(256) void cam_softmax_fused(
    const float* __restrict__ egy_part, float* __restrict__ egy)
{
    const int b   = blockIdx.x;
    const int rg  = blockIdx.y;
    const int t   = threadIdx.x;
    const int row = (rg << 4) + (t >> 4);
    const int jg  = t & 15;

    float e[8];
#pragma unroll
    for (int jj = 0; jj < 8; jj++) e[jj] = 0.f;
    for (int seg = 0; seg < 8; seg++) {
        const float* p = egy_part + (((size_t)(seg * 8 + b)) << 14) + row * 128 + (jg << 3);
#pragma unroll
        for (int jj = 0; jj < 8; jj++) e[jj] += p[jj];
    }
    float mn = e[0];
#pragma unroll
    for (int jj = 1; jj < 8; jj++) mn = fminf(mn, e[jj]);
#pragma unroll
    for (int k = 1; k < 16; k <<= 1) mn = fminf(mn, __shfl_xor(mn, k));
    float s = 0.f;
#pragma unroll
    for (int jj = 0; jj < 8; jj++) { float p = __expf(mn - e[jj]); e[jj] = p; s += p; }
#pragma unroll
    for (int k = 1; k < 16; k <<= 1) s += __shfl_xor(s, k);
    const float inv = 1.f / s;
    float* orow = egy + ((size_t)b << 14) + row * 128 + (jg << 3);
#pragma unroll
    for (int jj = 0; jj < 8; jj++) orow[jj] = e[jj] * inv;
}

// ---- PAM Q/K producer ----
__global__ __launch_bounds__(256) void pam_qk_1x1(
    const float* __restrict__ A, const float* __restrict__ Wb, const float* __restrict__ bb,
    const float* __restrict__ Wc, const float* __restrict__ bc,
    unsigned short* __restrict__ qt, unsigned short* __restrict__ kt)
{
    __shared__ float wl[2 * 16 * 128];
    __shared__ float bl[32];
    const int t = threadIdx.x;
    const int n = (blockIdx.x << 8) + t;
    const int b = blockIdx.y;
    for (int idx = t; idx < 2048; idx += 256) { wl[idx] = Wb[idx]; wl[2048 + idx] = Wc[idx]; }
    if (t < 16) { bl[t] = bb[t]; bl[16 + t] = bc[t]; }
    __syncthreads();
    float ab[16], ac[16];
#pragma unroll
    for (int k = 0; k < 16; k++) { ab[k] = 0.f; ac[k] = 0.f; }
    for (int chn = 0; chn < 128; ++chn) {
        float a = A[(((size_t)b * 128 + chn) << 12) + n];
#pragma unroll
        for (int k = 0; k < 16; k++) {
            ab[k] = fmaf(wl[k * 128 + chn], a, ab[k]);
            ac[k] = fmaf(wl[2048 + k * 128 + chn], a, ac[k]);
        }
    }
    unsigned short uq[16], uk[16];
#pragma unroll
    for (int k = 0; k < 16; k++) {
        uq[k] = f2bf(ab[k] + bl[k]);
        uk[k] = f2bf(ac[k] + bl[16 + k]);
    }
    size_t row = (size_t)b * 4096 + n;
    ((uint4*)qt)[row * 2 + 0] = ((uint4*)uq)[0];
    ((uint4*)qt)[row * 2 + 1] = ((uint4*)uq)[1];
    ((uint4*)kt)[row * 2 + 0] = ((uint4*)uk)[0];
    ((uint4*)kt)[row * 2 + 1] = ((uint4*)uk)[1];
}

// ---- PAM V producer: out m-blocked [b][m/16][c][16] bf16 ------------------
__global__ __launch_bounds__(256) void pam_v_1x1(
    const float* __restrict__ A, const float* __restrict__ Wd, const float* __restrict__ bd,
    unsigned short* __restrict__ vbB)
{
    __shared__ float wl[32 * 128];
    __shared__ float bl[32];
    const int t   = threadIdx.x;
    const int n   = (blockIdx.x << 8) + t;
    const int co0 = blockIdx.y << 5;
    const int b   = blockIdx.z;
    for (int idx = t; idx < 4096; idx += 256) {
        int c2 = idx >> 7, chv = idx & 127;
        wl[idx] = Wd[(co0 + c2) * 128 + chv];
    }
    if (t < 32) bl[t] = bd[co0 + t];
    __syncthreads();
    float acc[32];
#pragma unroll
    for (int k = 0; k < 32; k++) acc[k] = 0.f;
    for (int chn = 0; chn < 128; ++chn) {
        float a = A[(((size_t)b * 128 + chn) << 12) + n];
#pragma unroll
        for (int k = 0; k < 32; k++) acc[k] = fmaf(wl[k * 128 + chn], a, acc[k]);
    }
    const size_t mbase = (((size_t)b * 256 + (n >> 4)) * 128 + co0) * 16 + (n & 15);
#pragma unroll
    for (int k = 0; k < 32; k++)
        vbB[mbase + (size_t)k * 16] = f2bf(acc[k] + bl[k]);
}

// ---- PAM rowmax (global over all m) ----
__global__ __launch_bounds__(256) void pam_rowmax(
    const unsigned short* __restrict__ qt, const unsigned short* __restrict__ kt,
    float* __restrict__ rowmax)
{
    const int t  = threadIdx.x;
    const int w  = t >> 6;
    const int L  = t & 63;
    const int ln = L & 31;
    const int g  = L >> 5;
    const int b  = blockIdx.y;
    const int n0 = blockIdx.x << 5;
    __shared__ float red[4][32];

    const f32x16 zero = {0,0,0,0,0,0,0,0,0,0,0,0,0,0,0,0};
    short8 qfrag = *(const short8*)(qt + (((size_t)b * 4096 + n0 + ln) << 4) + (g << 3));

    float mx = -INFINITY;
    for (int mq = (w << 5); mq < 4096; mq += 128) {
        short8 kfrag = *(const short8*)(kt + (((size_t)b * 4096 + mq + ln) << 4) + (g << 3));
        f32x16 s = __builtin_amdgcn_mfma_f32_32x32x16_bf16(kfrag, qfrag, zero, 0, 0, 0);
#pragma unroll
        for (int r = 0; r < 16; r++) mx = fmaxf(mx, s[r]);
    }
    mx = fmaxf(mx, __shfl_xor(mx, 32));
    if (L < 32) red[w][L] = mx;
    __syncthreads();
    if (t < 32) {
        float m = fmaxf(fmaxf(red[0][t], red[1][t]), fmaxf(red[2][t], red[3][t]));
        rowmax[((size_t)b << 12) + n0 + t] = m;
    }
}

// ---- PAM attention, m-split partials. grid (128 n-tiles, 2 m-halves, 8 b) -
__global__ __launch_bounds__(256) void pam_attn_mfma(
    const unsigned short* __restrict__ qt, const unsigned short* __restrict__ kt,
    const unsigned short* __restrict__ vbB, const float* __restrict__ rowmax,
    float* __restrict__ part, float* __restrict__ lsum)
{
    const int t  = threadIdx.x;
    const int w  = t >> 6;
    const int L  = t & 63;
    const int ln = L & 31;
    const int g  = L >> 5;
    const int mh = blockIdx.y;
    const int b  = blockIdx.z;
    const int n0 = blockIdx.x << 5;
    const int c0 = w << 5;

    __shared__ unsigned short Pf[16 * 256];
    __shared__ float red[4][32];

    const f32x16 zero = {0,0,0,0,0,0,0,0,0,0,0,0,0,0,0,0};
    short8 qfrag = *(const short8*)(qt + (((size_t)b * 4096 + n0 + ln) << 4) + (g << 3));
    const float rm = rowmax[((size_t)b << 12) + n0 + ln];

    f32x16 acc = zero;
    float rs = 0.f;

    const int mbeg = mh << 11;
    for (int m0 = mbeg; m0 < mbeg + 2048; m0 += 128) {
        const int mq = m0 + (w << 5);
        short8 kfrag = *(const short8*)(kt + (((size_t)b * 4096 + mq + ln) << 4) + (g << 3));
        f32x16 s = __builtin_amdgcn_mfma_f32_32x32x16_bf16(kfrag, qfrag, zero, 0, 0, 0);

        float p[16];
#pragma unroll
        for (int r = 0; r < 16; r++) { p[r] = __expf(s[r] - rm); rs += p[r]; }
        float xx[16];
#pragma unroll
        for (int r = 0; r < 16; r++) xx[r] = __shfl_xor(p[r], 32);

        unsigned short f0[8], f1[8];
#pragma unroll
        for (int i = 0; i < 4; i++) {
            f0[i]     = f2bf(g ? xx[4 + i]  : p[i]);
            f0[4 + i] = f2bf(g ? p[4 + i]   : xx[i]);
            f1[i]     = f2bf(g ? xx[12 + i] : p[8 + i]);
            f1[4 + i] = f2bf(g ? p[12 + i]  : xx[8 + i]);
        }
        *(short8*)(&Pf[((w << 2) + g) * 256 + (ln << 3)])     = *(short8*)f0;
        *(short8*)(&Pf[((w << 2) + 2 + g) * 256 + (ln << 3)]) = *(short8*)f1;
        __syncthreads();

        const int mc0 = m0 >> 4;
#pragma unroll
        for (int kk = 0; kk < 8; kk++) {
            short8 pfrag = *(const short8*)(&Pf[((kk << 1) + g) * 256 + (ln << 3)]);
            short8 vfrag = *(const short8*)(vbB + (((size_t)b * 256 + mc0 + kk) * 128
                                                    + c0 + ln) * 16 + (g << 3));
            acc = __builtin_amdgcn_mfma_f32_32x32x16_bf16(vfrag, pfrag, acc, 0, 0, 0);
        }
        __syncthreads();
    }

    rs += __shfl_xor(rs, 32);
    if (L < 32) red[w][L] = rs;
    __syncthreads();
    if (t < 32)
        lsum[(((size_t)(mh * 8 + b)) << 12) + n0 + t]
            = red[0][t] + red[1][t] + red[2][t] + red[3][t];

    const int n = n0 + ln;
#pragma unroll
    for (int r = 0; r < 16; r++) {
        int c = c0 + (r & 3) + ((r >> 2) << 3) + (g << 2);
        part[((((size_t)(mh * 8 + b)) * 128 + c) << 12) + n] = acc[r];
    }
}

// ---- PAM combine: out = bf16( alpha*(p0+p1)/(l0+l1) + Y ), blocked --------
__global__ __launch_bounds__(256) void pam_combine(
    const float* __restrict__ part, const float* __restrict__ lsum,
    const float* __restrict__ alpha, const float* __restrict__ Y,
    unsigned short* __restrict__ outb)
{
    const int t = threadIdx.x;
    const int n = (blockIdx.x << 8) + t;
    const int b = blockIdx.y;
    const size_t h1 = (size_t)8 * 128 * 4096;   // mh=1 offset in part
    const float l = lsum[((size_t)b << 12) + n] + lsum[(((size_t)(8 + b)) << 12) + n];
    const float sc = alpha[0] / l;
#pragma unroll 1
    for (int cg = 0; cg < 8; ++cg) {
        unsigned short o[16];
#pragma unroll
        for (int j = 0; j < 16; ++j) {
            const int c = (cg << 4) + j;
            const size_t idx = (((size_t)b * 128 + c) << 12) + n;
            float v = fmaf(sc, part[idx] + part[h1 + idx], Y[idx]);
            o[j] = f2bf(v);
        }
        size_t dst = ((((size_t)b * 8 + cg) << 12) + n) << 4;
        *(uint4*)(outb + dst)     = ((uint4*)o)[0];
        *(uint4*)(outb + dst + 8) = ((uint4*)o)[1];
    }
}

// ---- CAM feat: in = bh/blo (channel-major), out = blocked hi/lo bf16 ------
__global__ __launch_bounds__(256) void cam_feat(
    const float* __restrict__ attn, const unsigned short* __restrict__ bh,
    const unsigned short* __restrict__ blo, const float* __restrict__ beta,
    unsigned short* __restrict__ camh, unsigned short* __restrict__ caml)
{
    const int t  = threadIdx.x;
    const int n  = (blockIdx.x << 8) + t;
    const int c0 = blockIdx.y << 5;
    const int b  = blockIdx.z;
    __shared__ float al[32 * 128];
    for (int idx = t; idx < 4096; idx += 256)
        al[idx] = attn[((size_t)b << 14) + (c0 + (idx >> 7)) * 128 + (idx & 127)];
    __syncthreads();
    float acc[32];
#pragma unroll
    for (int k = 0; k < 32; k++) acc[k] = 0.f;
    for (int d = 0; d < 128; ++d) {
        size_t idx = (((size_t)b * 128 + d) << 12) + n;
        float v = bf2f(bh[idx]) + bf2f(blo[idx]);
#pragma unroll
        for (int k = 0; k < 32; k++) acc[k] = fmaf(al[k * 128 + d], v, acc[k]);
    }
    float be = beta[0];
    unsigned short oh[32], ol[32];
#pragma unroll
    for (int k = 0; k < 32; k++) {
        size_t idx = (((size_t)b * 128 + c0 + k) << 12) + n;
        float bfv = bf2f(bh[idx]) + bf2f(blo[idx]);
        float v = fmaf(be, acc[k], bfv);
        unsigned short hi = f2bf(v);
        oh[k] = hi;
        ol[k] = f2bf(v - bf2f(hi));
    }
    const int g0 = c0 >> 4;
    size_t d0 = ((((size_t)b * 8 + g0) << 12) + n) << 4;
    size_t d1 = ((((size_t)b * 8 + g0 + 1) << 12) + n) << 4;
    *(uint4*)(camh + d0)     = ((uint4*)oh)[0];
    *(uint4*)(camh + d0 + 8) = ((uint4*)oh)[1];
    *(uint4*)(camh + d1)     = ((uint4*)oh)[2];
    *(uint4*)(camh + d1 + 8) = ((uint4*)oh)[3];
    *(uint4*)(caml + d0)     = ((uint4*)ol)[0];
    *(uint4*)(caml + d0 + 8) = ((uint4*)ol)[1];
    *(uint4*)(caml + d1)     = ((uint4*)ol)[2];
    *(uint4*)(caml + d1 + 8) = ((uint4*)ol)[3];
}

// ---- Final heads ----
__global__ __launch_bounds__(256) void heads(
    const float* __restrict__ FP, const float* __restrict__ FC,
    const float* __restrict__ Wout, const float* __restrict__ bout,
    const float* __restrict__ Wp3, const float* __restrict__ bp3,
    const float* __restrict__ Wc3, const float* __restrict__ bc3,
    float* __restrict__ out)
{
    const int t = threadIdx.x;
    const int n = (blockIdx.x << 8) + t;
    const int b = blockIdx.y;
    __shared__ float wl[3 * 19 * 128];
    __shared__ float bl[3 * 19];
    for (int idx = t; idx < 2432; idx += 256) {
        wl[idx]        = Wout[idx];
        wl[2432 + idx] = Wp3[idx];
        wl[4864 + idx] = Wc3[idx];
    }
    if (t < 19) { bl[t] = bout[t]; bl[19 + t] = bp3[t]; bl[38 + t] = bc3[t]; }
    __syncthreads();
    float am[19], ap[19], ac[19];
#pragma unroll
    for (int o = 0; o < 19; o++) { am[o] = 0.f; ap[o] = 0.f; ac[o] = 0.f; }
    for (int chn = 0; chn < 128; ++chn) {
        float pv = FP[(((size_t)b * 128 + chn) << 12) + n];
        float cv = FC[(((size_t)b * 128 + chn) << 12) + n];
        float fv = pv + cv;
#pragma unroll
        for (int o = 0; o < 19; o++) {
            am[o] = fmaf(wl[o * 128 + chn], fv, am[o]);
            ap[o] = fmaf(wl[2432 + o * 128 + chn], pv, ap[o]);
            ac[o] = fmaf(wl[4864 + o * 128 + chn], cv, ac[o]);
        }
    }
    const size_t OS = (size_t)8 * 19 * 4096;
#pragma unroll
    for (int o = 0; o < 19; o++) {
        size_t base = (((size_t)b * 19 + o) << 12) + n;
        out[base]          = 1.f / (1.f + __expf(-(am[o] + bl[o])));
        out[OS + base]     = 1.f / (1.f + __expf(-(ap[o] + bl[19 + o])));
        out[2 * OS + base] = 1.f / (1.f + __expf(-(ac[o] + bl[38 + o])));
    }
}

extern "C" void kernel_launch(void* const* d_in, const int* in_sizes, int n_in,
                              void* d_out, int out_size, void* d_ws, size_t ws_size,
                              hipStream_t stream)
{
    const float* x     = (const float*)d_in[0];
    const float* Wp1   = (const float*)d_in[1];
    const float* bnp1  = (const float*)d_in[2];
    const float* Wc1   = (const float*)d_in[3];
    const float* bnc1  = (const float*)d_in[4];
    const float* Wb    = (const float*)d_in[5];
    const float* bb    = (const float*)d_in[6];
    const float* Wc    = (const float*)d_in[7];
    const float* bcv   = (const float*)d_in[8];
    const float* Wd    = (const float*)d_in[9];
    const float* bd    = (const float*)d_in[10];
    const float* alpha = (const float*)d_in[11];
    const float* beta  = (const float*)d_in[12];
    const float* Wp2   = (const float*)d_in[13];
    const float* bnp2  = (const float*)d_in[14];
    const float* Wc2   = (const float*)d_in[15];
    const float* bnc2  = (const float*)d_in[16];
    const float* Wout  = (const float*)d_in[17];
    const float* bo    = (const float*)d_in[18];
    const float* Wp3   = (const float*)d_in[19];
    const float* bp3   = (const float*)d_in[20];
    const float* Wc3   = (const float*)d_in[21];
    const float* bc3   = (const float*)d_in[22];
    float* out = (float*)d_out;

    char* ws = (char*)d_ws;
    const size_t MB = 1u << 20;
    const size_t W1SZ = (size_t)32 * 18432 * 2;   // 1.125 MB
    const size_t W2SZ = (size_t)8 * 18432 * 2;    // 288 KB
    float*          bufA     = (float*)(ws);                     // conv1p out (Y) -> conv2c out
    unsigned short* bh       = (unsigned short*)(ws + 16 * MB);
    unsigned short* blo      = (unsigned short*)(ws + 24 * MB);
    unsigned short* xh       = (unsigned short*)(ws + 32 * MB);  // 32MB, dead after conv1c
    unsigned short* xl       = (unsigned short*)(ws + 64 * MB);  // 32MB, dead after conv1c
    float*          egy_part = (float*)(ws + 32 * MB);           // 4MB
    unsigned short* qt       = (unsigned short*)(ws + 36 * MB);
    unsigned short* kt       = (unsigned short*)(ws + 37 * MB);
    float*          rowmax   = (float*)(ws + 38 * MB);
    float*          egy      = (float*)(ws + 38 * MB + (1u << 17));
    unsigned short* vbB      = (unsigned short*)(ws + 39 * MB);  // 8MB m-blocked
    float*          part     = (float*)(ws + 47 * MB);           // 32MB (2 halves)
    float*          lsum     = (float*)(ws + 79 * MB);           // 256KB
    unsigned short* pam_bfB  = (unsigned short*)(ws + 80 * MB);  // 8MB blocked
    float*          bufD     = (float*)(ws + 47 * MB);           // 16MB (after combine)
    unsigned short* camh     = (unsigned short*)(ws + 63 * MB);  // 8MB (after combine)
    unsigned short* caml     = (unsigned short*)(ws + 71 * MB);  // 8MB
    unsigned short* wp1      = (unsigned short*)(ws + 96 * MB);  // OUTSIDE xl (R7 bug fix)
    unsigned short* wc1h     = (unsigned short*)(ws + 96 * MB + W1SZ);
    unsigned short* wc1l     = (unsigned short*)(ws + 96 * MB + 2 * W1SZ);
    unsigned short* wp2      = (unsigned short*)(ws + 96 * MB + 3 * W1SZ);
    unsigned short* wc2h     = (unsigned short*)(ws + 96 * MB + 3 * W1SZ + W2SZ);
    unsigned short* wc2l     = (unsigned short*)(ws + 96 * MB + 3 * W1SZ + 2 * W2SZ);

    dim3 blk(256);
    const int n1 = 32 * 18432;
    const int n2 = 8 * 18432;
    wpack_kernel<<<dim3((n1 + 255) / 256), blk, 0, stream>>>(Wp1, wp1, 512, n1);
    wpack_kernel<<<dim3((n2 + 255) / 256), blk, 0, stream>>>(Wp2, wp2, 128, n2);
    wpack_split_kernel<<<dim3((n1 + 255) / 256), blk, 0, stream>>>(Wc1, wc1h, wc1l, 512, n1);
    wpack_split_kernel<<<dim3((n2 + 255) / 256), blk, 0, stream>>>(Wc2, wc2h, wc2l, 128, n2);

    x_split_kernel<<<dim3(32, 8), blk, 0, stream>>>(x, xh, xl);

    conv3x3_mfma<<<dim3(32, 2, 8), blk, 0, stream>>>(xh, 512, wp1, bnp1, bufA);
    conv3x3_mfma_hilo<<<dim3(32, 2, 8), blk, 0, stream>>>(xh, xl, 512, wc1h, wc1l, bnc1,
                                                          (float*)0, bh, blo);
    cam_energy_mfma<<<dim3(16, 8, 8), blk, 0, stream>>>(bh, blo, egy_part);
    cam_softmax_fused<<<dim3(8, 8), blk, 0, stream>>>(egy_part, egy);

    pam_qk_1x1<<<dim3(16, 8), blk, 0, stream>>>(bufA, Wb, bb, Wc, bcv, qt, kt);
    pam_v_1x1<<<dim3(16, 4, 8), blk, 0, stream>>>(bufA, Wd, bd, vbB);
    pam_rowmax<<<dim3(128, 8), blk, 0, stream>>>(qt, kt, rowmax);
    pam_attn_mfma<<<dim3(128, 2, 8), blk, 0, stream>>>(qt, kt, vbB, rowmax, part, lsum);
    pam_combine<<<dim3(16, 8), blk, 0, stream>>>(part, lsum, alpha, bufA, pam_bfB);

    conv3x3_mfma<<<dim3(32, 2, 8), blk, 0, stream>>>(pam_bfB, 128, wp2, bnp2, bufD);

    cam_feat<<<dim3(16, 4, 8), blk, 0, stream>>>(egy, bh, blo, beta, camh, caml);
    conv3x3_mfma_hilo<<<dim3(32, 2, 8), blk, 0, stream>>>(camh, caml, 128, wc2h, wc2l, bnc2,
                                                          bufA, (unsigned short*)0, (unsigned short*)0);

    heads<<<dim3(16, 8), blk, 0, stream>>>(bufD, bufA, Wout, bo, Wp3, bp3, Wc3, bc3, out);
}